// Round 15
// baseline (213.559 us; speedup 1.0000x reference)
//
#include <hip/hip_runtime.h>
#include <math.h>

// ---------------------------------------------------------------------------
// GCRN-GRU with H0=0 collapses to:
//   Xh = x@pre_w + pre_b                      (bf16 MFMA GEMM, K=128) -> Xq
//   LX = lap(Xh)                              (bin-quarter gather)    -> LXc
//   [Z|T]pre = [Xq|LXc] @ Bcat (256x256)      (bf16 MFMA GEMM, K=256)
//   h  = relu((1-sigmoid(Zpre))*tanh(Tpre))   (fused epilogue, bf16 out)
//   out[i] = dot(h[a]*h[b], pwsum) + pbsum    (bf16 gather decoder)
// R15: R14 + scatter TLP fix only. Scatter phase ran 196 blocks x 4 waves
// (1 block/CU, occ 16%) -- fully exposed latency. RND 4096->2048 doubles
// scatter blocks (392); 16-barrier scan ladder -> hierarchical wave shfl
// scan (2 barriers); scatter LDS 25.6->14.4 KB. All else identical to R14.
// ---------------------------------------------------------------------------

#define RND 2048
#define EPT 8            // RND/256
#define SORT_CAP 1536
#define CAPB 6144

typedef __attribute__((ext_vector_type(4))) float f32x4;
typedef __attribute__((ext_vector_type(8))) short short8;

static __device__ __forceinline__ unsigned short f2b(float f) {
  union { float f; unsigned u; } v; v.f = f;
  unsigned r = (v.u + 0x7fffu + ((v.u >> 16) & 1u)) >> 16;  // RNE
  return (unsigned short)r;
}
static __device__ __forceinline__ float b2f(unsigned short s) {
  union { unsigned u; float f; } v; v.u = ((unsigned)s) << 16;
  return v.f;
}

// Build bf16 weight images + fused biases + pwsum; init deg=0, binPos=b*CAPB.
__global__ __launch_bounds__(256) void prep_kernel(const float* __restrict__ pre_w, const float* __restrict__ Wx,
                                                   const float* __restrict__ bx, const float* __restrict__ bh,
                                                   const float* __restrict__ post_w, const float* __restrict__ post_b,
                                                   unsigned short* __restrict__ Bt1c, unsigned short* __restrict__ Btc2,
                                                   float* __restrict__ fb2, float* __restrict__ pwsum,
                                                   int* __restrict__ deg, int* __restrict__ binPos, int N) {
  int e = blockIdx.x * 256 + threadIdx.x;
  const int TOT = gridDim.x * 256;
  for (int i = e; i < N; i += TOT) deg[i] = 0;
  if (e < 256) binPos[e] = e * CAPB;
  if (e < 16384) {
    int kc = e >> 12, r = e & 4095, col = r >> 5, kk = r & 31;
    Bt1c[e] = f2b(pre_w[(kc * 32 + kk) * 128 + col]);
  }
  int e2 = e - 16384;
  if (e2 >= 0 && e2 < 65536) {
    int kc = e2 >> 13, r = e2 & 8191, cB = r >> 5, kk = r & 31;
    int k = kc * 32 + kk, half = k >> 7, ki = k & 127;
    int cb = cB >> 7, r7 = cB & 127, nw6 = r7 >> 6, u2 = r7 & 63;
    int g = (u2 >= 32) ? 2 : 0, hcol = cb * 64 + nw6 * 32 + (u2 & 31);
    Btc2[e2] = f2b(Wx[((g * 2 + half) * 128 + ki) * 128 + hcol]);
  }
  int e3 = e - (16384 + 65536);
  if (e3 >= 0 && e3 < 256) {
    int cB = e3;
    int cb = cB >> 7, r7 = cB & 127, nw6 = r7 >> 6, u2 = r7 & 63;
    int g = (u2 >= 32) ? 2 : 0, hcol = cb * 64 + nw6 * 32 + (u2 & 31);
    fb2[cB] = bx[g * 128 + hcol] + bh[g * 128 + hcol];
  }
  int e4 = e - (16384 + 65536 + 256);
  if (e4 >= 0 && e4 < 128) pwsum[e4] = post_w[2 * e4] + post_w[2 * e4 + 1];
  if (e4 == 128) pwsum[128] = post_b[0] + post_b[1];
}

// LDS overlay for the two mega1 personalities.
union SMemU {
  struct { unsigned short As[128 * 40]; unsigned short Bs[128 * 40]; } g;          // 20480 B
  struct { unsigned ent[RND]; int hist[256], lstart[256], lofs[256], gbase[256],
           wsum[4]; unsigned char ebin[RND]; } s;                                  // ~14.4 KB
};

// Fused: blocks [0,RB) = gemm1; blocks [RB, RB+SCAT) = scatter (LDS local sort).
__global__ __launch_bounds__(256) void mega1_kernel(const float* __restrict__ x,
                                                    const unsigned short* __restrict__ Bt1c,
                                                    const float* __restrict__ pre_b,
                                                    unsigned short* __restrict__ Xq,
                                                    const int* __restrict__ ei, int* __restrict__ binPos,
                                                    unsigned* __restrict__ bins, int* __restrict__ deg,
                                                    int N, int E, int RB) {
  __shared__ SMemU sm;
  const int t = threadIdx.x;

  if ((int)blockIdx.x < RB) {
    // ---------------- gemm1 personality ----------------
    unsigned short* As = sm.g.As;
    unsigned short* Bs = sm.g.Bs;
    const int r0 = blockIdx.x * 128;
    const int w = t >> 6, lane = t & 63;
    const int m = lane & 15, q = lane >> 4;
    const int mw = (w >> 1) * 64, nw = (w & 1) * 64;

    f32x4 acc[4][4];
#pragma unroll
    for (int i = 0; i < 4; ++i)
#pragma unroll
      for (int j = 0; j < 4; ++j) acc[i][j] = {0.f, 0.f, 0.f, 0.f};

    const int arow = t >> 1, aseg = t & 1;
    const bool arow_ok = (r0 + arow) < N;
    const float* asrc0 = &x[(size_t)(r0 + arow) * 128 + aseg * 16];

    float4 cav[4]; short8 cbv0, cbv1;
    {
      if (arow_ok) {
#pragma unroll
        for (int i = 0; i < 4; ++i) cav[i] = *(const float4*)(asrc0 + i * 4);
      } else {
#pragma unroll
        for (int i = 0; i < 4; ++i) cav[i] = make_float4(0.f, 0.f, 0.f, 0.f);
      }
      const char* src = (const char*)Bt1c + t * 32;
      cbv0 = *(const short8*)src;
      cbv1 = *(const short8*)(src + 16);
    }

    for (int kc = 0; kc < 4; ++kc) {
      __syncthreads();
      {
        short8 t0, t1;
#pragma unroll
        for (int i = 0; i < 2; ++i) {
          t0[i * 4 + 0] = (short)f2b(cav[i].x); t0[i * 4 + 1] = (short)f2b(cav[i].y);
          t0[i * 4 + 2] = (short)f2b(cav[i].z); t0[i * 4 + 3] = (short)f2b(cav[i].w);
          t1[i * 4 + 0] = (short)f2b(cav[i + 2].x); t1[i * 4 + 1] = (short)f2b(cav[i + 2].y);
          t1[i * 4 + 2] = (short)f2b(cav[i + 2].z); t1[i * 4 + 3] = (short)f2b(cav[i + 2].w);
        }
        *(short8*)&As[arow * 40 + aseg * 16] = t0;
        *(short8*)&As[arow * 40 + aseg * 16 + 8] = t1;
        int bcol = t >> 1, boff = (t & 1) * 16;
        *(short8*)&Bs[bcol * 40 + boff] = cbv0;
        *(short8*)&Bs[bcol * 40 + boff + 8] = cbv1;
      }
      float4 nav[4]; short8 nbv0, nbv1;
      if (kc < 3) {
        if (arow_ok) {
          const float* src = asrc0 + (kc + 1) * 32;
#pragma unroll
          for (int i = 0; i < 4; ++i) nav[i] = *(const float4*)(src + i * 4);
        } else {
#pragma unroll
          for (int i = 0; i < 4; ++i) nav[i] = make_float4(0.f, 0.f, 0.f, 0.f);
        }
        const char* src = (const char*)Bt1c + (size_t)(kc + 1) * 8192 + t * 32;
        nbv0 = *(const short8*)src;
        nbv1 = *(const short8*)(src + 16);
      }
      __syncthreads();
      short8 af[4], bf[4];
#pragma unroll
      for (int i = 0; i < 4; ++i) af[i] = *(const short8*)&As[(mw + i * 16 + m) * 40 + q * 8];
#pragma unroll
      for (int j = 0; j < 4; ++j) bf[j] = *(const short8*)&Bs[(nw + j * 16 + m) * 40 + q * 8];
#pragma unroll
      for (int i = 0; i < 4; ++i)
#pragma unroll
        for (int j = 0; j < 4; ++j)
          acc[i][j] = __builtin_amdgcn_mfma_f32_16x16x32_bf16(af[i], bf[j], acc[i][j], 0, 0, 0);
      if (kc < 3) {
#pragma unroll
        for (int i = 0; i < 4; ++i) cav[i] = nav[i];
        cbv0 = nbv0; cbv1 = nbv1;
      }
    }

#pragma unroll
    for (int i = 0; i < 4; ++i) {
      int rb2 = r0 + mw + i * 16 + q * 4;
#pragma unroll
      for (int j = 0; j < 4; ++j) {
        int col = nw + j * 16 + m;
        float bias = pre_b[col];
#pragma unroll
        for (int r = 0; r < 4; ++r) {
          int row = rb2 + r;
          if (row < N) Xq[(size_t)row * 128 + col] = f2b(acc[i][j][r] + bias);
        }
      }
    }
    return;
  }

  // ---------------- scatter personality (LDS local sort, RND=2048) ----------------
  unsigned* ent = sm.s.ent;
  unsigned char* ebin = sm.s.ebin;
  int* hist = sm.s.hist;
  int* lstart = sm.s.lstart;
  int* lofs = sm.s.lofs;
  int* gbase = sm.s.gbase;
  int* wsum = sm.s.wsum;
  const int sbid = (int)blockIdx.x - RB;
  const int snum = (int)gridDim.x - RB;
  const int lane = t & 63, wv = t >> 6;
  for (long long base = (long long)sbid * RND; base < E; base += (long long)snum * RND) {
    int cnt = (int)(((long long)E - base < RND) ? (E - base) : RND);
    if (t < 256) hist[t] = 0;
    __syncthreads();
    unsigned my_e[EPT]; int my_b[EPT];
#pragma unroll
    for (int u = 0; u < EPT; ++u) {
      int i = u * 256 + t;
      my_b[u] = -1;
      if (i < cnt) {
        int idx = (int)base + i;
        int s = ei[idx], d = ei[E + idx];
        atomicAdd(&deg[s], 1);
        my_b[u] = d >> 8;
        my_e[u] = (unsigned)s | ((unsigned)(d & 255) << 16);
        atomicAdd(&hist[my_b[u]], 1);
      }
    }
    __syncthreads();
    // Hierarchical exclusive scan over 256 bins: wave shfl + cross-wave fixup.
    int h = hist[t];
    int v = h;
#pragma unroll
    for (int d = 1; d < 64; d <<= 1) {
      int u2 = __shfl_up(v, d);
      if (lane >= d) v += u2;
    }
    if (lane == 63) wsum[wv] = v;
    __syncthreads();
    int woff = 0;
#pragma unroll
    for (int w2 = 0; w2 < 4; ++w2) if (w2 < wv) woff += wsum[w2];
    int excl = woff + v - h;
    lstart[t] = excl;
    lofs[t] = excl;
    if (h > 0) gbase[t] = atomicAdd(&binPos[t], h);
    __syncthreads();
#pragma unroll
    for (int u = 0; u < EPT; ++u) {
      if (my_b[u] >= 0) {
        int p = atomicAdd(&lofs[my_b[u]], 1);
        ent[p] = my_e[u];
        ebin[p] = (unsigned char)my_b[u];
      }
    }
    __syncthreads();
    for (int i = t; i < cnt; i += 256) {
      int b = ebin[i];
      int pos = gbase[b] + (i - lstart[b]);
      if (pos < (b + 1) * CAPB) bins[pos] = ent[i];   // guard: statistically never taken
    }
    __syncthreads();
  }
}

// One block per 64-node QUARTER of a 256-node bin (grid = NBIN*4, 512 thr).
// Bin edge list staged to LDS once (hist pass); fill pass reads LDS.
// 64-wide prefix scan in wave 0 via __shfl_up (1 barrier). dinv inline.
__global__ __launch_bounds__(512) void lap_bin_kernel(const unsigned short* __restrict__ Xq,
                                                      unsigned short* __restrict__ LXc,
                                                      const unsigned* __restrict__ bins,
                                                      const int* __restrict__ binPos,
                                                      const int* __restrict__ deg, int N) {
  __shared__ unsigned eLDS[CAPB];              // 24576 B
  __shared__ unsigned short sortS[SORT_CAP];
  __shared__ float sortW[SORT_CAP];
  __shared__ int hist[64], start[64], off[64];
  const int t = threadIdx.x;
  const int bin = blockIdx.x >> 2, qt = blockIdx.x & 3;
  const int lo = bin * CAPB;
  int T = binPos[bin] - lo;
  if (T > CAPB) T = CAPB;
  const unsigned* __restrict__ ebase = &bins[lo];
  if (t < 64) hist[t] = 0;
  __syncthreads();
  // Pass 1: stage to LDS + histogram this quarter.
  for (int i = t; i < T; i += 512) {
    unsigned e = ebase[i];
    eLDS[i] = e;
    int dl = (e >> 16) & 255;
    if ((dl >> 6) == qt) atomicAdd(&hist[dl & 63], 1);
  }
  __syncthreads();
  // Wave-0 exclusive scan over 64 entries (no internal barriers).
  if (t < 64) {
    int h = hist[t];
    int v = h;
#pragma unroll
    for (int d = 1; d < 64; d <<= 1) {
      int u = __shfl_up(v, d);
      if (t >= d) v += u;
    }
    start[t] = v - h;
    off[t] = v - h;
  }
  __syncthreads();
  // Pass 2: fill CSR from LDS copy.
  for (int i = t; i < T; i += 512) {
    unsigned e = eLDS[i];
    int dl = (e >> 16) & 255;
    if ((dl >> 6) == qt) {
      int s = (int)(e & 0xFFFFu);
      int p = atomicAdd(&off[dl & 63], 1);
      if (p < SORT_CAP) {
        int dg = deg[s];
        sortS[p] = (unsigned short)s;
        sortW[p] = dg > 0 ? rsqrtf((float)dg) : 0.0f;
      }
    }
  }
  __syncthreads();
  const int wv = t >> 6, lane = t & 63;
  for (int n = wv; n < 64; n += 8) {
    int node = bin * 256 + qt * 64 + n;
    if (node >= N) break;
    int st = start[n], cnum = hist[n];
    float ax = 0.f, ay = 0.f;
    for (int j = 0; j < cnum; j += 8) {
      unsigned v[8]; float ws[8];
#pragma unroll
      for (int u = 0; u < 8; ++u) {
        int idx = j + u;
        int s = 0; float w = 0.f;
        if (idx < cnum) { s = sortS[st + idx]; w = sortW[st + idx]; }
        ws[u] = w;
        v[u] = *(const unsigned*)((const char*)Xq + (size_t)s * 256 + lane * 4);
      }
#pragma unroll
      for (int u = 0; u < 8; ++u) {
        union { unsigned u32; float f; } fl, fh;
        fl.u32 = v[u] << 16; fh.u32 = v[u] & 0xffff0000u;
        ax += ws[u] * fl.f;
        ay += ws[u] * fh.f;
      }
    }
    int dgn = deg[node];
    float wd = dgn > 0 ? -rsqrtf((float)dgn) : 0.0f;
    unsigned o = (unsigned)f2b(ax * wd) | ((unsigned)f2b(ay * wd) << 16);
    *(unsigned*)((char*)LXc + (size_t)node * 256 + lane * 4) = o;
  }
}

// [Z|T]pre = [Xq|LXc] @ Btc2, fused sigmoid/tanh/relu -> h bf16. Pipelined.
__global__ __launch_bounds__(256) void gemm2_mfma(const unsigned short* __restrict__ Xq,
                                                  const unsigned short* __restrict__ LXc,
                                                  const unsigned short* __restrict__ Btc2,
                                                  const float* __restrict__ fb2,
                                                  unsigned short* __restrict__ hb, int N) {
  __shared__ unsigned short As[128 * 40];
  __shared__ unsigned short Bs[128 * 40];
  const int t = threadIdx.x;
  const int rb = blockIdx.x >> 1, cb = blockIdx.x & 1;
  const int r0 = rb * 128;
  const int w = t >> 6, lane = t & 63;
  const int m = lane & 15, q = lane >> 4;
  const int mw = (w >> 1) * 64, nw = (w & 1) * 64;

  f32x4 acc[4][4];
#pragma unroll
  for (int i = 0; i < 4; ++i)
#pragma unroll
    for (int j = 0; j < 4; ++j) acc[i][j] = {0.f, 0.f, 0.f, 0.f};

  const int arow = t >> 1;
  const int aoff = (t & 1) * 32;
  const char* aXq = (const char*)Xq + (size_t)(r0 + arow) * 256 + aoff;
  const char* aLX = (const char*)LXc + (size_t)(r0 + arow) * 256 + aoff;
  const char* bsrc0 = (const char*)Btc2 + (size_t)cb * 8192 + t * 32;

  short8 cav0, cav1, cbv0, cbv1;
  cav0 = *(const short8*)aXq;
  cav1 = *(const short8*)(aXq + 16);
  cbv0 = *(const short8*)bsrc0;
  cbv1 = *(const short8*)(bsrc0 + 16);

  for (int kc = 0; kc < 8; ++kc) {
    __syncthreads();
    *(short8*)&As[arow * 40 + (aoff >> 1)] = cav0;
    *(short8*)&As[arow * 40 + (aoff >> 1) + 8] = cav1;
    {
      int bcol = t >> 1, boff = (t & 1) * 16;
      *(short8*)&Bs[bcol * 40 + boff] = cbv0;
      *(short8*)&Bs[bcol * 40 + boff + 8] = cbv1;
    }
    short8 nav0, nav1, nbv0, nbv1;
    if (kc < 7) {
      int kn = kc + 1;
      const char* asrc = (kn < 4) ? (aXq + kn * 64) : (aLX + (kn - 4) * 64);
      nav0 = *(const short8*)asrc;
      nav1 = *(const short8*)(asrc + 16);
      const char* bsrc = bsrc0 + (size_t)kn * 16384;
      nbv0 = *(const short8*)bsrc;
      nbv1 = *(const short8*)(bsrc + 16);
    }
    __syncthreads();
    short8 af[4], bf[4];
#pragma unroll
    for (int i = 0; i < 4; ++i) af[i] = *(const short8*)&As[(mw + i * 16 + m) * 40 + q * 8];
#pragma unroll
    for (int j = 0; j < 4; ++j) bf[j] = *(const short8*)&Bs[(nw + j * 16 + m) * 40 + q * 8];
#pragma unroll
    for (int i = 0; i < 4; ++i)
#pragma unroll
      for (int j = 0; j < 4; ++j)
        acc[i][j] = __builtin_amdgcn_mfma_f32_16x16x32_bf16(af[i], bf[j], acc[i][j], 0, 0, 0);
    if (kc < 7) { cav0 = nav0; cav1 = nav1; cbv0 = nbv0; cbv1 = nbv1; }
  }

#pragma unroll
  for (int i = 0; i < 4; ++i) {
    int rbase = r0 + mw + i * 16 + q * 4;
#pragma unroll
    for (int jz = 0; jz < 2; ++jz) {
      int cBz = cb * 128 + nw + jz * 16 + m;
      int hc = cb * 64 + (nw >> 1) + jz * 16 + m;
      float bz = fb2[cBz], bt = fb2[cBz + 32];
#pragma unroll
      for (int r = 0; r < 4; ++r) {
        int row = rbase + r;
        if (row < N) {
          float zp = acc[i][jz][r] + bz;
          float tp = acc[i][jz + 2][r] + bt;
          float zs = 1.0f / (1.0f + __expf(-zp));
          float th = tanhf(tp);
          hb[(size_t)row * 128 + hc] = f2b(fmaxf((1.0f - zs) * th, 0.0f));
        }
      }
    }
  }
}

// out[i] = dot(h[a]*h[b], pwsum) + pwsum[128].  16 lanes/edge, 8 bf16 each.
__global__ __launch_bounds__(256) void decoder_kernel(const unsigned short* __restrict__ hb,
                                                      const int* __restrict__ eli,
                                                      const float* __restrict__ pwsum, float* __restrict__ out, int M) {
  int t = threadIdx.x;
  int i = blockIdx.x * 16 + (t >> 4);
  int l = t & 15;
  if (i >= M) return;
  int a = eli[i], b = eli[M + i];
  int k = l * 8;
  short8 va = *(const short8*)&hb[(size_t)a * 128 + k];
  short8 vb = *(const short8*)&hb[(size_t)b * 128 + k];
  const float4* pwp = (const float4*)&pwsum[k];
  float4 p0 = pwp[0], p1 = pwp[1];
  float s = 0.0f;
  s += b2f((unsigned short)va[0]) * b2f((unsigned short)vb[0]) * p0.x;
  s += b2f((unsigned short)va[1]) * b2f((unsigned short)vb[1]) * p0.y;
  s += b2f((unsigned short)va[2]) * b2f((unsigned short)vb[2]) * p0.z;
  s += b2f((unsigned short)va[3]) * b2f((unsigned short)vb[3]) * p0.w;
  s += b2f((unsigned short)va[4]) * b2f((unsigned short)vb[4]) * p1.x;
  s += b2f((unsigned short)va[5]) * b2f((unsigned short)vb[5]) * p1.y;
  s += b2f((unsigned short)va[6]) * b2f((unsigned short)vb[6]) * p1.z;
  s += b2f((unsigned short)va[7]) * b2f((unsigned short)vb[7]) * p1.w;
#pragma unroll
  for (int off = 8; off; off >>= 1) s += __shfl_xor(s, off);
  if (l == 0) out[i] = s + pwsum[128];
}

extern "C" void kernel_launch(void* const* d_in, const int* in_sizes, int n_in,
                              void* d_out, int out_size, void* d_ws, size_t ws_size,
                              hipStream_t stream) {
  const float* x      = (const float*)d_in[0];
  const int*   ei     = (const int*)d_in[1];
  const int*   eli    = (const int*)d_in[2];
  const float* pre_w  = (const float*)d_in[3];
  const float* pre_b  = (const float*)d_in[4];
  const float* Wx     = (const float*)d_in[5];
  const float* bx     = (const float*)d_in[6];
  const float* bh     = (const float*)d_in[8];
  const float* post_w = (const float*)d_in[9];
  const float* post_b = (const float*)d_in[10];
  float* out = (float*)d_out;

  const int N = in_sizes[0] / 128;
  const int E = in_sizes[1] / 2;
  const int M = in_sizes[2] / 2;
  const int RB = (N + 127) / 128;
  const int NBIN = (N + 255) / 256;   // 196 for N=50000 (s fits in 16 bits: N<=65536)
  const int SCAT = (E + RND - 1) / RND;

  char* W = (char*)d_ws;
  size_t o = 0;
  int* deg = (int*)(W + o);       o += (size_t)N * 4;
  int* binPos = (int*)(W + o);    o += 1024;
  o = (o + 255) & ~(size_t)255;
  unsigned* bins = (unsigned*)(W + o); o += (size_t)NBIN * CAPB * 4;
  o = (o + 255) & ~(size_t)255;
  unsigned short* Xq = (unsigned short*)(W + o);  o += (size_t)RB * 128 * 256;  // compact Xh
  unsigned short* LXc = (unsigned short*)(W + o); o += (size_t)RB * 128 * 256;  // compact LX
  unsigned short* hb = (unsigned short*)(W + o);  o += (size_t)N * 256;
  unsigned short* Bt1c = (unsigned short*)(W + o); o += 32768;
  unsigned short* Btc2 = (unsigned short*)(W + o); o += 131072;
  float* fb2 = (float*)(W + o);  o += 1024;
  float* pwsum = (float*)(W + o); o += 768;

  prep_kernel<<<322, 256, 0, stream>>>(pre_w, Wx, bx, bh, post_w, post_b, Bt1c, Btc2, fb2, pwsum,
                                       deg, binPos, N);
  mega1_kernel<<<RB + SCAT, 256, 0, stream>>>(x, Bt1c, pre_b, Xq, ei, binPos, bins, deg, N, E, RB);
  lap_bin_kernel<<<NBIN * 4, 512, 0, stream>>>(Xq, LXc, bins, binPos, deg, N);
  gemm2_mfma<<<RB * 2, 256, 0, stream>>>(Xq, LXc, Btc2, fb2, hb, N);
  decoder_kernel<<<(M + 15) / 16, 256, 0, stream>>>(hb, eli, pwsum, out, M);
}

// Round 16
// 209.819 us; speedup vs baseline: 1.0178x; 1.0178x over previous
//
#include <hip/hip_runtime.h>
#include <math.h>

// ---------------------------------------------------------------------------
// GCRN-GRU with H0=0 collapses to:
//   Xh = x@pre_w + pre_b                      (bf16 MFMA GEMM, K=128) -> Xq
//   LX = lap(Xh)                              (bin-quarter gather)    -> LXc
//   [Z|T]pre = [Xq|LXc] @ Bcat (256x256)      (bf16 MFMA GEMM, K=256)
//   h  = relu((1-sigmoid(Zpre))*tanh(Tpre))   (fused epilogue, bf16 out)
//   out[i] = dot(h[a]*h[b], pwsum) + pbsum    (bf16 gather decoder)
// FINAL (R14 config, measured best 211.4us): R10 structure + lap_bin LDS
// staging + wave-shfl scan. R11/R12/R13/R15 restructures all regressed:
// the partition+gather pipeline is scattered-op-volume bound (TCC ceiling),
// invariant to barriers/TLP/store pattern; gathers sit at L3 request floor.
// ---------------------------------------------------------------------------

#define RND 4096
#define SORT_CAP 1536
#define CAPB 6144

typedef __attribute__((ext_vector_type(4))) float f32x4;
typedef __attribute__((ext_vector_type(8))) short short8;

static __device__ __forceinline__ unsigned short f2b(float f) {
  union { float f; unsigned u; } v; v.f = f;
  unsigned r = (v.u + 0x7fffu + ((v.u >> 16) & 1u)) >> 16;  // RNE
  return (unsigned short)r;
}
static __device__ __forceinline__ float b2f(unsigned short s) {
  union { unsigned u; float f; } v; v.u = ((unsigned)s) << 16;
  return v.f;
}

// Build bf16 weight images + fused biases + pwsum; init deg=0, binPos=b*CAPB.
__global__ __launch_bounds__(256) void prep_kernel(const float* __restrict__ pre_w, const float* __restrict__ Wx,
                                                   const float* __restrict__ bx, const float* __restrict__ bh,
                                                   const float* __restrict__ post_w, const float* __restrict__ post_b,
                                                   unsigned short* __restrict__ Bt1c, unsigned short* __restrict__ Btc2,
                                                   float* __restrict__ fb2, float* __restrict__ pwsum,
                                                   int* __restrict__ deg, int* __restrict__ binPos, int N) {
  int e = blockIdx.x * 256 + threadIdx.x;
  const int TOT = gridDim.x * 256;
  for (int i = e; i < N; i += TOT) deg[i] = 0;
  if (e < 256) binPos[e] = e * CAPB;
  if (e < 16384) {
    int kc = e >> 12, r = e & 4095, col = r >> 5, kk = r & 31;
    Bt1c[e] = f2b(pre_w[(kc * 32 + kk) * 128 + col]);
  }
  int e2 = e - 16384;
  if (e2 >= 0 && e2 < 65536) {
    int kc = e2 >> 13, r = e2 & 8191, cB = r >> 5, kk = r & 31;
    int k = kc * 32 + kk, half = k >> 7, ki = k & 127;
    int cb = cB >> 7, r7 = cB & 127, nw6 = r7 >> 6, u2 = r7 & 63;
    int g = (u2 >= 32) ? 2 : 0, hcol = cb * 64 + nw6 * 32 + (u2 & 31);
    Btc2[e2] = f2b(Wx[((g * 2 + half) * 128 + ki) * 128 + hcol]);
  }
  int e3 = e - (16384 + 65536);
  if (e3 >= 0 && e3 < 256) {
    int cB = e3;
    int cb = cB >> 7, r7 = cB & 127, nw6 = r7 >> 6, u2 = r7 & 63;
    int g = (u2 >= 32) ? 2 : 0, hcol = cb * 64 + nw6 * 32 + (u2 & 31);
    fb2[cB] = bx[g * 128 + hcol] + bh[g * 128 + hcol];
  }
  int e4 = e - (16384 + 65536 + 256);
  if (e4 >= 0 && e4 < 128) pwsum[e4] = post_w[2 * e4] + post_w[2 * e4 + 1];
  if (e4 == 128) pwsum[128] = post_b[0] + post_b[1];
}

// LDS overlay for the two mega1 personalities (R10 form).
union SMemU {
  struct { unsigned short As[128 * 40]; unsigned short Bs[128 * 40]; } g;          // 20480 B
  struct { unsigned ent[RND]; int hist[256], scanbuf[256], lstart[256],
           lofs[256], gbase[256]; unsigned char ebin[RND]; } s;                    // 25600 B
};

// Fused: blocks [0,RB) = gemm1; blocks [RB, RB+SCAT) = scatter (LDS local sort).
__global__ __launch_bounds__(256) void mega1_kernel(const float* __restrict__ x,
                                                    const unsigned short* __restrict__ Bt1c,
                                                    const float* __restrict__ pre_b,
                                                    unsigned short* __restrict__ Xq,
                                                    const int* __restrict__ ei, int* __restrict__ binPos,
                                                    unsigned* __restrict__ bins, int* __restrict__ deg,
                                                    int N, int E, int RB) {
  __shared__ SMemU sm;
  const int t = threadIdx.x;

  if ((int)blockIdx.x < RB) {
    // ---------------- gemm1 personality ----------------
    unsigned short* As = sm.g.As;
    unsigned short* Bs = sm.g.Bs;
    const int r0 = blockIdx.x * 128;
    const int w = t >> 6, lane = t & 63;
    const int m = lane & 15, q = lane >> 4;
    const int mw = (w >> 1) * 64, nw = (w & 1) * 64;

    f32x4 acc[4][4];
#pragma unroll
    for (int i = 0; i < 4; ++i)
#pragma unroll
      for (int j = 0; j < 4; ++j) acc[i][j] = {0.f, 0.f, 0.f, 0.f};

    const int arow = t >> 1, aseg = t & 1;
    const bool arow_ok = (r0 + arow) < N;
    const float* asrc0 = &x[(size_t)(r0 + arow) * 128 + aseg * 16];

    float4 cav[4]; short8 cbv0, cbv1;
    {
      if (arow_ok) {
#pragma unroll
        for (int i = 0; i < 4; ++i) cav[i] = *(const float4*)(asrc0 + i * 4);
      } else {
#pragma unroll
        for (int i = 0; i < 4; ++i) cav[i] = make_float4(0.f, 0.f, 0.f, 0.f);
      }
      const char* src = (const char*)Bt1c + t * 32;
      cbv0 = *(const short8*)src;
      cbv1 = *(const short8*)(src + 16);
    }

    for (int kc = 0; kc < 4; ++kc) {
      __syncthreads();
      {
        short8 t0, t1;
#pragma unroll
        for (int i = 0; i < 2; ++i) {
          t0[i * 4 + 0] = (short)f2b(cav[i].x); t0[i * 4 + 1] = (short)f2b(cav[i].y);
          t0[i * 4 + 2] = (short)f2b(cav[i].z); t0[i * 4 + 3] = (short)f2b(cav[i].w);
          t1[i * 4 + 0] = (short)f2b(cav[i + 2].x); t1[i * 4 + 1] = (short)f2b(cav[i + 2].y);
          t1[i * 4 + 2] = (short)f2b(cav[i + 2].z); t1[i * 4 + 3] = (short)f2b(cav[i + 2].w);
        }
        *(short8*)&As[arow * 40 + aseg * 16] = t0;
        *(short8*)&As[arow * 40 + aseg * 16 + 8] = t1;
        int bcol = t >> 1, boff = (t & 1) * 16;
        *(short8*)&Bs[bcol * 40 + boff] = cbv0;
        *(short8*)&Bs[bcol * 40 + boff + 8] = cbv1;
      }
      float4 nav[4]; short8 nbv0, nbv1;
      if (kc < 3) {
        if (arow_ok) {
          const float* src = asrc0 + (kc + 1) * 32;
#pragma unroll
          for (int i = 0; i < 4; ++i) nav[i] = *(const float4*)(src + i * 4);
        } else {
#pragma unroll
          for (int i = 0; i < 4; ++i) nav[i] = make_float4(0.f, 0.f, 0.f, 0.f);
        }
        const char* src = (const char*)Bt1c + (size_t)(kc + 1) * 8192 + t * 32;
        nbv0 = *(const short8*)src;
        nbv1 = *(const short8*)(src + 16);
      }
      __syncthreads();
      short8 af[4], bf[4];
#pragma unroll
      for (int i = 0; i < 4; ++i) af[i] = *(const short8*)&As[(mw + i * 16 + m) * 40 + q * 8];
#pragma unroll
      for (int j = 0; j < 4; ++j) bf[j] = *(const short8*)&Bs[(nw + j * 16 + m) * 40 + q * 8];
#pragma unroll
      for (int i = 0; i < 4; ++i)
#pragma unroll
        for (int j = 0; j < 4; ++j)
          acc[i][j] = __builtin_amdgcn_mfma_f32_16x16x32_bf16(af[i], bf[j], acc[i][j], 0, 0, 0);
      if (kc < 3) {
#pragma unroll
        for (int i = 0; i < 4; ++i) cav[i] = nav[i];
        cbv0 = nbv0; cbv1 = nbv1;
      }
    }

#pragma unroll
    for (int i = 0; i < 4; ++i) {
      int rb2 = r0 + mw + i * 16 + q * 4;
#pragma unroll
      for (int j = 0; j < 4; ++j) {
        int col = nw + j * 16 + m;
        float bias = pre_b[col];
#pragma unroll
        for (int r = 0; r < 4; ++r) {
          int row = rb2 + r;
          if (row < N) Xq[(size_t)row * 128 + col] = f2b(acc[i][j][r] + bias);
        }
      }
    }
    return;
  }

  // ---------------- scatter personality (R10: LDS local sort) ----------------
  unsigned* ent = sm.s.ent;
  unsigned char* ebin = sm.s.ebin;
  int* hist = sm.s.hist;
  int* scanbuf = sm.s.scanbuf;
  int* lstart = sm.s.lstart;
  int* lofs = sm.s.lofs;
  int* gbase = sm.s.gbase;
  const int sbid = (int)blockIdx.x - RB;
  const int snum = (int)gridDim.x - RB;
  for (long long base = (long long)sbid * RND; base < E; base += (long long)snum * RND) {
    int cnt = (int)(((long long)E - base < RND) ? (E - base) : RND);
    if (t < 256) hist[t] = 0;
    __syncthreads();
    unsigned my_e[16]; int my_b[16];
#pragma unroll
    for (int u = 0; u < 16; ++u) {
      int i = u * 256 + t;
      my_b[u] = -1;
      if (i < cnt) {
        int idx = (int)base + i;
        int s = ei[idx], d = ei[E + idx];
        atomicAdd(&deg[s], 1);
        my_b[u] = d >> 8;
        my_e[u] = (unsigned)s | ((unsigned)(d & 255) << 16);
        atomicAdd(&hist[my_b[u]], 1);
      }
    }
    __syncthreads();
    scanbuf[t] = hist[t];
    __syncthreads();
    for (int d = 1; d < 256; d <<= 1) {
      int v = (t >= d) ? scanbuf[t - d] : 0;
      __syncthreads();
      scanbuf[t] += v;
      __syncthreads();
    }
    int excl = scanbuf[t] - hist[t];
    lstart[t] = excl;
    lofs[t] = excl;
    if (hist[t] > 0) gbase[t] = atomicAdd(&binPos[t], hist[t]);
    __syncthreads();
#pragma unroll
    for (int u = 0; u < 16; ++u) {
      if (my_b[u] >= 0) {
        int p = atomicAdd(&lofs[my_b[u]], 1);
        ent[p] = my_e[u];
        ebin[p] = (unsigned char)my_b[u];
      }
    }
    __syncthreads();
    for (int i = t; i < cnt; i += 256) {
      int b = ebin[i];
      int pos = gbase[b] + (i - lstart[b]);
      if (pos < (b + 1) * CAPB) bins[pos] = ent[i];   // guard: statistically never taken
    }
    __syncthreads();
  }
}

// One block per 64-node QUARTER of a 256-node bin (grid = NBIN*4, 512 thr).
// Bin edge list staged to LDS once (hist pass); fill pass reads LDS.
// 64-wide prefix scan in wave 0 via __shfl_up (1 barrier). dinv inline.
__global__ __launch_bounds__(512) void lap_bin_kernel(const unsigned short* __restrict__ Xq,
                                                      unsigned short* __restrict__ LXc,
                                                      const unsigned* __restrict__ bins,
                                                      const int* __restrict__ binPos,
                                                      const int* __restrict__ deg, int N) {
  __shared__ unsigned eLDS[CAPB];              // 24576 B
  __shared__ unsigned short sortS[SORT_CAP];
  __shared__ float sortW[SORT_CAP];
  __shared__ int hist[64], start[64], off[64];
  const int t = threadIdx.x;
  const int bin = blockIdx.x >> 2, qt = blockIdx.x & 3;
  const int lo = bin * CAPB;
  int T = binPos[bin] - lo;
  if (T > CAPB) T = CAPB;
  const unsigned* __restrict__ ebase = &bins[lo];
  if (t < 64) hist[t] = 0;
  __syncthreads();
  // Pass 1: stage to LDS + histogram this quarter.
  for (int i = t; i < T; i += 512) {
    unsigned e = ebase[i];
    eLDS[i] = e;
    int dl = (e >> 16) & 255;
    if ((dl >> 6) == qt) atomicAdd(&hist[dl & 63], 1);
  }
  __syncthreads();
  // Wave-0 exclusive scan over 64 entries (no internal barriers).
  if (t < 64) {
    int h = hist[t];
    int v = h;
#pragma unroll
    for (int d = 1; d < 64; d <<= 1) {
      int u = __shfl_up(v, d);
      if (t >= d) v += u;
    }
    start[t] = v - h;
    off[t] = v - h;
  }
  __syncthreads();
  // Pass 2: fill CSR from LDS copy.
  for (int i = t; i < T; i += 512) {
    unsigned e = eLDS[i];
    int dl = (e >> 16) & 255;
    if ((dl >> 6) == qt) {
      int s = (int)(e & 0xFFFFu);
      int p = atomicAdd(&off[dl & 63], 1);
      if (p < SORT_CAP) {
        int dg = deg[s];
        sortS[p] = (unsigned short)s;
        sortW[p] = dg > 0 ? rsqrtf((float)dg) : 0.0f;
      }
    }
  }
  __syncthreads();
  const int wv = t >> 6, lane = t & 63;
  for (int n = wv; n < 64; n += 8) {
    int node = bin * 256 + qt * 64 + n;
    if (node >= N) break;
    int st = start[n], cnum = hist[n];
    float ax = 0.f, ay = 0.f;
    for (int j = 0; j < cnum; j += 8) {
      unsigned v[8]; float ws[8];
#pragma unroll
      for (int u = 0; u < 8; ++u) {
        int idx = j + u;
        int s = 0; float w = 0.f;
        if (idx < cnum) { s = sortS[st + idx]; w = sortW[st + idx]; }
        ws[u] = w;
        v[u] = *(const unsigned*)((const char*)Xq + (size_t)s * 256 + lane * 4);
      }
#pragma unroll
      for (int u = 0; u < 8; ++u) {
        union { unsigned u32; float f; } fl, fh;
        fl.u32 = v[u] << 16; fh.u32 = v[u] & 0xffff0000u;
        ax += ws[u] * fl.f;
        ay += ws[u] * fh.f;
      }
    }
    int dgn = deg[node];
    float wd = dgn > 0 ? -rsqrtf((float)dgn) : 0.0f;
    unsigned o = (unsigned)f2b(ax * wd) | ((unsigned)f2b(ay * wd) << 16);
    *(unsigned*)((char*)LXc + (size_t)node * 256 + lane * 4) = o;
  }
}

// [Z|T]pre = [Xq|LXc] @ Btc2, fused sigmoid/tanh/relu -> h bf16. Pipelined.
__global__ __launch_bounds__(256) void gemm2_mfma(const unsigned short* __restrict__ Xq,
                                                  const unsigned short* __restrict__ LXc,
                                                  const unsigned short* __restrict__ Btc2,
                                                  const float* __restrict__ fb2,
                                                  unsigned short* __restrict__ hb, int N) {
  __shared__ unsigned short As[128 * 40];
  __shared__ unsigned short Bs[128 * 40];
  const int t = threadIdx.x;
  const int rb = blockIdx.x >> 1, cb = blockIdx.x & 1;
  const int r0 = rb * 128;
  const int w = t >> 6, lane = t & 63;
  const int m = lane & 15, q = lane >> 4;
  const int mw = (w >> 1) * 64, nw = (w & 1) * 64;

  f32x4 acc[4][4];
#pragma unroll
  for (int i = 0; i < 4; ++i)
#pragma unroll
    for (int j = 0; j < 4; ++j) acc[i][j] = {0.f, 0.f, 0.f, 0.f};

  const int arow = t >> 1;
  const int aoff = (t & 1) * 32;
  const char* aXq = (const char*)Xq + (size_t)(r0 + arow) * 256 + aoff;
  const char* aLX = (const char*)LXc + (size_t)(r0 + arow) * 256 + aoff;
  const char* bsrc0 = (const char*)Btc2 + (size_t)cb * 8192 + t * 32;

  short8 cav0, cav1, cbv0, cbv1;
  cav0 = *(const short8*)aXq;
  cav1 = *(const short8*)(aXq + 16);
  cbv0 = *(const short8*)bsrc0;
  cbv1 = *(const short8*)(bsrc0 + 16);

  for (int kc = 0; kc < 8; ++kc) {
    __syncthreads();
    *(short8*)&As[arow * 40 + (aoff >> 1)] = cav0;
    *(short8*)&As[arow * 40 + (aoff >> 1) + 8] = cav1;
    {
      int bcol = t >> 1, boff = (t & 1) * 16;
      *(short8*)&Bs[bcol * 40 + boff] = cbv0;
      *(short8*)&Bs[bcol * 40 + boff + 8] = cbv1;
    }
    short8 nav0, nav1, nbv0, nbv1;
    if (kc < 7) {
      int kn = kc + 1;
      const char* asrc = (kn < 4) ? (aXq + kn * 64) : (aLX + (kn - 4) * 64);
      nav0 = *(const short8*)asrc;
      nav1 = *(const short8*)(asrc + 16);
      const char* bsrc = bsrc0 + (size_t)kn * 16384;
      nbv0 = *(const short8*)bsrc;
      nbv1 = *(const short8*)(bsrc + 16);
    }
    __syncthreads();
    short8 af[4], bf[4];
#pragma unroll
    for (int i = 0; i < 4; ++i) af[i] = *(const short8*)&As[(mw + i * 16 + m) * 40 + q * 8];
#pragma unroll
    for (int j = 0; j < 4; ++j) bf[j] = *(const short8*)&Bs[(nw + j * 16 + m) * 40 + q * 8];
#pragma unroll
    for (int i = 0; i < 4; ++i)
#pragma unroll
      for (int j = 0; j < 4; ++j)
        acc[i][j] = __builtin_amdgcn_mfma_f32_16x16x32_bf16(af[i], bf[j], acc[i][j], 0, 0, 0);
    if (kc < 7) { cav0 = nav0; cav1 = nav1; cbv0 = nbv0; cbv1 = nbv1; }
  }

#pragma unroll
  for (int i = 0; i < 4; ++i) {
    int rbase = r0 + mw + i * 16 + q * 4;
#pragma unroll
    for (int jz = 0; jz < 2; ++jz) {
      int cBz = cb * 128 + nw + jz * 16 + m;
      int hc = cb * 64 + (nw >> 1) + jz * 16 + m;
      float bz = fb2[cBz], bt = fb2[cBz + 32];
#pragma unroll
      for (int r = 0; r < 4; ++r) {
        int row = rbase + r;
        if (row < N) {
          float zp = acc[i][jz][r] + bz;
          float tp = acc[i][jz + 2][r] + bt;
          float zs = 1.0f / (1.0f + __expf(-zp));
          float th = tanhf(tp);
          hb[(size_t)row * 128 + hc] = f2b(fmaxf((1.0f - zs) * th, 0.0f));
        }
      }
    }
  }
}

// out[i] = dot(h[a]*h[b], pwsum) + pwsum[128].  16 lanes/edge, 8 bf16 each.
__global__ __launch_bounds__(256) void decoder_kernel(const unsigned short* __restrict__ hb,
                                                      const int* __restrict__ eli,
                                                      const float* __restrict__ pwsum, float* __restrict__ out, int M) {
  int t = threadIdx.x;
  int i = blockIdx.x * 16 + (t >> 4);
  int l = t & 15;
  if (i >= M) return;
  int a = eli[i], b = eli[M + i];
  int k = l * 8;
  short8 va = *(const short8*)&hb[(size_t)a * 128 + k];
  short8 vb = *(const short8*)&hb[(size_t)b * 128 + k];
  const float4* pwp = (const float4*)&pwsum[k];
  float4 p0 = pwp[0], p1 = pwp[1];
  float s = 0.0f;
  s += b2f((unsigned short)va[0]) * b2f((unsigned short)vb[0]) * p0.x;
  s += b2f((unsigned short)va[1]) * b2f((unsigned short)vb[1]) * p0.y;
  s += b2f((unsigned short)va[2]) * b2f((unsigned short)vb[2]) * p0.z;
  s += b2f((unsigned short)va[3]) * b2f((unsigned short)vb[3]) * p0.w;
  s += b2f((unsigned short)va[4]) * b2f((unsigned short)vb[4]) * p1.x;
  s += b2f((unsigned short)va[5]) * b2f((unsigned short)vb[5]) * p1.y;
  s += b2f((unsigned short)va[6]) * b2f((unsigned short)vb[6]) * p1.z;
  s += b2f((unsigned short)va[7]) * b2f((unsigned short)vb[7]) * p1.w;
#pragma unroll
  for (int off = 8; off; off >>= 1) s += __shfl_xor(s, off);
  if (l == 0) out[i] = s + pwsum[128];
}

extern "C" void kernel_launch(void* const* d_in, const int* in_sizes, int n_in,
                              void* d_out, int out_size, void* d_ws, size_t ws_size,
                              hipStream_t stream) {
  const float* x      = (const float*)d_in[0];
  const int*   ei     = (const int*)d_in[1];
  const int*   eli    = (const int*)d_in[2];
  const float* pre_w  = (const float*)d_in[3];
  const float* pre_b  = (const float*)d_in[4];
  const float* Wx     = (const float*)d_in[5];
  const float* bx     = (const float*)d_in[6];
  const float* bh     = (const float*)d_in[8];
  const float* post_w = (const float*)d_in[9];
  const float* post_b = (const float*)d_in[10];
  float* out = (float*)d_out;

  const int N = in_sizes[0] / 128;
  const int E = in_sizes[1] / 2;
  const int M = in_sizes[2] / 2;
  const int RB = (N + 127) / 128;
  const int NBIN = (N + 255) / 256;   // 196 for N=50000 (s fits in 16 bits: N<=65536)
  const int SCAT = (E + RND - 1) / RND;

  char* W = (char*)d_ws;
  size_t o = 0;
  int* deg = (int*)(W + o);       o += (size_t)N * 4;
  int* binPos = (int*)(W + o);    o += 1024;
  o = (o + 255) & ~(size_t)255;
  unsigned* bins = (unsigned*)(W + o); o += (size_t)NBIN * CAPB * 4;
  o = (o + 255) & ~(size_t)255;
  unsigned short* Xq = (unsigned short*)(W + o);  o += (size_t)RB * 128 * 256;  // compact Xh
  unsigned short* LXc = (unsigned short*)(W + o); o += (size_t)RB * 128 * 256;  // compact LX
  unsigned short* hb = (unsigned short*)(W + o);  o += (size_t)N * 256;
  unsigned short* Bt1c = (unsigned short*)(W + o); o += 32768;
  unsigned short* Btc2 = (unsigned short*)(W + o); o += 131072;
  float* fb2 = (float*)(W + o);  o += 1024;
  float* pwsum = (float*)(W + o); o += 768;

  prep_kernel<<<322, 256, 0, stream>>>(pre_w, Wx, bx, bh, post_w, post_b, Bt1c, Btc2, fb2, pwsum,
                                       deg, binPos, N);
  mega1_kernel<<<RB + SCAT, 256, 0, stream>>>(x, Bt1c, pre_b, Xq, ei, binPos, bins, deg, N, E, RB);
  lap_bin_kernel<<<NBIN * 4, 512, 0, stream>>>(Xq, LXc, bins, binPos, deg, N);
  gemm2_mfma<<<RB * 2, 256, 0, stream>>>(Xq, LXc, Btc2, fb2, hb, N);
  decoder_kernel<<<(M + 15) / 16, 256, 0, stream>>>(hb, eli, pwsum, out, M);
}